// Round 4
// baseline (107.324 us; speedup 1.0000x reference)
//
#include <hip/hip_runtime.h>

#define BATCH 8192
#define NUM_SV 8192
#define DIM 256
#define GAMMA 0.1f
#define LOG2E 1.4426950408889634f
// sqrt(2*GAMMA*LOG2E) : pre-scale so MFMA acc == log2-exponent contribution
#define ALPHA 0.53715827f

#define SCHUNK 8
#define NST 4                 // s-tiles per block
#define NKC 8                 // k-steps per s-tile (256/32)
#define NITER (NST * NKC)     // 32
#define TILE_F16 8192         // 256 rows * 32 k = 16KB per (tile,kc)

typedef _Float16 f16;
typedef __attribute__((ext_vector_type(8))) _Float16 f16x8;
typedef __attribute__((ext_vector_type(16))) float f32x16;

__device__ __forceinline__ void gload_lds16(const f16* g, f16* l) {
  __builtin_amdgcn_global_load_lds((const __attribute__((address_space(1))) void*)g,
                                   (__attribute__((address_space(3))) void*)l, 16, 0, 0);
}

// ---------------- pre-pass: scaled fp16 tiled copies + norms + dcp ----------
__global__ __launch_bounds__(256)
void svm_prep(const float* __restrict__ x, const float* __restrict__ sv,
              const float* __restrict__ dual,
              f16* __restrict__ x16, f16* __restrict__ sv16,
              float* __restrict__ xg, float* __restrict__ dcp) {
  const int id = blockIdx.x * 256 + threadIdx.x;
  const bool isx = id < (BATCH * DIM / 8);
  const int lid = isx ? id : id - (BATCH * DIM / 8);
  const int row = lid >> 5;
  const int k0  = (lid & 31) << 3;

  const float* src = (isx ? x : sv) + (size_t)row * DIM + k0;
  float4 u = *(const float4*)(src);
  float4 v = *(const float4*)(src + 4);

  float sq = u.x*u.x + u.y*u.y + u.z*u.z + u.w*u.w
           + v.x*v.x + v.y*v.y + v.z*v.z + v.w*v.w;
  #pragma unroll
  for (int m = 1; m <= 16; m <<= 1) sq += __shfl_xor(sq, m, 32);
  if ((lid & 31) == 0) {
    float g = -(GAMMA * LOG2E) * sq;
    if (isx) xg[row] = g;
    else     dcp[row] = dual[row] * __builtin_amdgcn_exp2f(g);
  }

  f16x8 h;
  h[0] = (f16)(ALPHA * u.x); h[1] = (f16)(ALPHA * u.y);
  h[2] = (f16)(ALPHA * u.z); h[3] = (f16)(ALPHA * u.w);
  h[4] = (f16)(ALPHA * v.x); h[5] = (f16)(ALPHA * v.y);
  h[6] = (f16)(ALPHA * v.z); h[7] = (f16)(ALPHA * v.w);

  const int bt = row >> 8;
  const int r  = row & 255;
  const int kc = k0 >> 5;
  const int c  = (k0 >> 3) & 3;
  f16* dst = (isx ? x16 : sv16) + (size_t)(bt * NKC + kc) * TILE_F16 + (c * 256 + r) * 8;
  *(f16x8*)dst = h;
}

// ---------------- main fused MFMA kernel (counted-vmcnt 3-deep pipeline) ----
// 512 threads = 8 waves (4 wb x 2 wn); wave tile 64 rows x 128 cols as
// 2x4 grid of mfma_f32_32x32x16_f16. Three 32KB LDS buffers; stage(t+2)
// issued at iter t; s_waitcnt vmcnt(4) (never 0 until the last iter) so
// prefetch stays in flight across barriers.
__global__ __launch_bounds__(512, 2)
void svm_main(const f16* __restrict__ x16, const f16* __restrict__ sv16,
              const float* __restrict__ dcp, float* __restrict__ partial) {
  __shared__ f16 lds[3][2 * TILE_F16];   // 96KB

  const int tid = threadIdx.x;
  const int w   = tid >> 6;
  const int l   = tid & 63;
  const int lr  = l & 31;
  const int lh  = l >> 5;
  const int wb  = w >> 1;        // 0..3 : 64-row strip
  const int wn  = w & 1;         // 0..1 : 128-col strip
  const int sch = blockIdx.x;    // 0..7  (XCD-local s-chunk)
  const int bt  = blockIdx.y;    // 0..31
  const int stile0 = sch * NST;

  // prefetch dual*exp(-g*|sv|^2) factors -> regs; keeps the main loop free of
  // any VMEM other than the stage batches (so vmcnt counting stays exact).
  float dvv[NST][4];
  #pragma unroll
  for (int st = 0; st < NST; ++st)
    #pragma unroll
    for (int n = 0; n < 4; ++n)
      dvv[st][n] = dcp[(stile0 + st) * 256 + wn * 128 + n * 32 + lr];

  auto stage = [&](f16* dst, int stile, int kc) {
    const f16* xb = x16  + (size_t)(bt * NKC + kc) * TILE_F16;
    const f16* sb = sv16 + (size_t)(stile * NKC + kc) * TILE_F16;
    #pragma unroll
    for (int j = 0; j < 4; ++j) {
      const int r = w * 4 + j;                       // wave-uniform chunk id
      const f16* src = (r < 16) ? (xb + r * 512 + l * 8)
                                : (sb + (r - 16) * 512 + l * 8);
      gload_lds16(src, dst + r * 512);
    }
  };

  float ctr[2][16];
  #pragma unroll
  for (int m = 0; m < 2; ++m)
    #pragma unroll
    for (int r = 0; r < 16; ++r) ctr[m][r] = 0.f;

  stage(&lds[0][0], stile0, 0);
  stage(&lds[1][0], stile0, 1);
  int ib = 0;

  #pragma unroll
  for (int st = 0; st < NST; ++st) {
    f32x16 acc[2][4];
    #pragma unroll
    for (int m = 0; m < 2; ++m)
      #pragma unroll
      for (int n = 0; n < 4; ++n)
        #pragma unroll
        for (int r = 0; r < 16; ++r) acc[m][n][r] = 0.f;

    for (int kc = 0; kc < NKC; ++kc) {
      // ---- phase boundary: wait stage(t) landed (keep stage(t+1) in flight)
      __builtin_amdgcn_sched_barrier(0);
      if (st < NST - 1 || kc < NKC - 1)
        asm volatile("s_waitcnt vmcnt(4)" ::: "memory");
      else
        asm volatile("s_waitcnt vmcnt(0)" ::: "memory");
      __builtin_amdgcn_s_barrier();
      __builtin_amdgcn_sched_barrier(0);

      // ---- issue stage(t+2) into the buffer read at t-1
      const int t2 = st * NKC + kc + 2;
      int ib2 = ib + 2; if (ib2 >= 3) ib2 -= 3;
      if (t2 < NITER)
        stage(&lds[ib2][0], stile0 + (t2 >> 3), t2 & 7);

      // ---- compute on buf[ib]: 2 phases of {6 ds_read_b128, 8 MFMA}
      const f16* buf = &lds[ib][0];
      #pragma unroll
      for (int ks = 0; ks < 2; ++ks) {
        const int ko = (ks * 2 + lh) * 256;
        f16x8 a0 = *(const f16x8*)&buf[(ko + wb * 64 +  0 + lr) * 8];
        f16x8 a1 = *(const f16x8*)&buf[(ko + wb * 64 + 32 + lr) * 8];
        f16x8 b0 = *(const f16x8*)&buf[TILE_F16 + (ko + wn * 128 +  0 + lr) * 8];
        f16x8 b1 = *(const f16x8*)&buf[TILE_F16 + (ko + wn * 128 + 32 + lr) * 8];
        f16x8 b2 = *(const f16x8*)&buf[TILE_F16 + (ko + wn * 128 + 64 + lr) * 8];
        f16x8 b3 = *(const f16x8*)&buf[TILE_F16 + (ko + wn * 128 + 96 + lr) * 8];
        __builtin_amdgcn_s_setprio(1);
        acc[0][0] = __builtin_amdgcn_mfma_f32_32x32x16_f16(a0, b0, acc[0][0], 0, 0, 0);
        acc[0][1] = __builtin_amdgcn_mfma_f32_32x32x16_f16(a0, b1, acc[0][1], 0, 0, 0);
        acc[0][2] = __builtin_amdgcn_mfma_f32_32x32x16_f16(a0, b2, acc[0][2], 0, 0, 0);
        acc[0][3] = __builtin_amdgcn_mfma_f32_32x32x16_f16(a0, b3, acc[0][3], 0, 0, 0);
        acc[1][0] = __builtin_amdgcn_mfma_f32_32x32x16_f16(a1, b0, acc[1][0], 0, 0, 0);
        acc[1][1] = __builtin_amdgcn_mfma_f32_32x32x16_f16(a1, b1, acc[1][1], 0, 0, 0);
        acc[1][2] = __builtin_amdgcn_mfma_f32_32x32x16_f16(a1, b2, acc[1][2], 0, 0, 0);
        acc[1][3] = __builtin_amdgcn_mfma_f32_32x32x16_f16(a1, b3, acc[1][3], 0, 0, 0);
        __builtin_amdgcn_s_setprio(0);
      }
      ib = ib + 1; if (ib >= 3) ib -= 3;
    }

    // ---- fused epilogue for s-tile st (registers only)
    #pragma unroll
    for (int n = 0; n < 4; ++n) {
      const float dv = dvv[st][n];
      #pragma unroll
      for (int m = 0; m < 2; ++m)
        #pragma unroll
        for (int r = 0; r < 16; ++r)
          ctr[m][r] = fmaf(__builtin_amdgcn_exp2f(acc[m][n][r]), dv, ctr[m][r]);
    }
  }

  // ---- reduce ctr across the 32 col-lanes sharing each row set
  #pragma unroll
  for (int m = 0; m < 2; ++m)
    #pragma unroll
    for (int r = 0; r < 16; ++r) {
      float v = ctr[m][r];
      v += __shfl_xor(v, 1, 64);
      v += __shfl_xor(v, 2, 64);
      v += __shfl_xor(v, 4, 64);
      v += __shfl_xor(v, 8, 64);
      v += __shfl_xor(v, 16, 64);
      ctr[m][r] = v;
    }

  __syncthreads();                         // LDS buffers free; reuse for red
  float* red = (float*)&lds[0][0];         // [2][256]
  if (lr == 0) {
    #pragma unroll
    for (int m = 0; m < 2; ++m)
      #pragma unroll
      for (int r = 0; r < 16; ++r) {
        const int rl = wb * 64 + m * 32 + (r & 3) + 8 * (r >> 2) + 4 * lh;
        red[wn * 256 + rl] = ctr[m][r];
      }
  }
  __syncthreads();
  if (tid < 256)
    partial[(size_t)sch * BATCH + bt * 256 + tid] = red[tid] + red[256 + tid];
}

// ---------------- final reduction + x-norm factor ----------------
__global__ __launch_bounds__(256)
void svm_reduce(const float* __restrict__ partial, const float* __restrict__ xg,
                float* __restrict__ out) {
  const int b = blockIdx.x * 256 + threadIdx.x;
  float s = 0.f;
  #pragma unroll
  for (int c = 0; c < SCHUNK; ++c) s += partial[(size_t)c * BATCH + b];
  out[b] = __builtin_amdgcn_exp2f(xg[b]) * s;
}

extern "C" void kernel_launch(void* const* d_in, const int* in_sizes, int n_in,
                              void* d_out, int out_size, void* d_ws, size_t ws_size,
                              hipStream_t stream) {
  const float* x    = (const float*)d_in[0];
  const float* sv   = (const float*)d_in[1];
  const float* dual = (const float*)d_in[2];
  float* out = (float*)d_out;

  f16*   x16     = (f16*)d_ws;                       // 4MB
  f16*   sv16    = x16 + (size_t)BATCH * DIM;        // 4MB
  float* xg      = (float*)(sv16 + (size_t)NUM_SV * DIM);
  float* dcp     = xg + BATCH;
  float* partial = dcp + NUM_SV;                     // SCHUNK * BATCH

  svm_prep<<<(BATCH + NUM_SV) * DIM / 8 / 256, 256, 0, stream>>>(x, sv, dual, x16, sv16, xg, dcp);
  svm_main<<<dim3(SCHUNK, BATCH / 256), 512, 0, stream>>>(x16, sv16, dcp, partial);
  svm_reduce<<<BATCH / 256, 256, 0, stream>>>(partial, xg, out);
}

// Round 5
// 60.759 us; speedup vs baseline: 1.7664x; 1.7664x over previous
//
#include <hip/hip_runtime.h>

#define BATCH 8192
#define NUM_SV 8192
#define DIM 256
#define GAMMA 0.1f
#define LOG2E 1.4426950408889634f
// sqrt(2*GAMMA*LOG2E) : pre-scale so MFMA acc == log2-exponent contribution
#define ALPHA 0.53715827f

#define SCHUNK 8
#define NST 4                 // s-tiles per block
#define NKC 8                 // k-steps per s-tile (256/32)
#define NITER (NST * NKC)     // 32
#define TILE_F16 8192         // 256 rows * 32 k = 16KB per (tile,kc)

typedef _Float16 f16;
typedef __attribute__((ext_vector_type(8))) _Float16 f16x8;
typedef __attribute__((ext_vector_type(16))) float f32x16;

__device__ __forceinline__ void gload_lds16(const f16* g, f16* l) {
  __builtin_amdgcn_global_load_lds((const __attribute__((address_space(1))) void*)g,
                                   (__attribute__((address_space(3))) void*)l, 16, 0, 0);
}

// ---------------- pre-pass: scaled fp16 tiled copies + norms + dcp ----------
__global__ __launch_bounds__(256)
void svm_prep(const float* __restrict__ x, const float* __restrict__ sv,
              const float* __restrict__ dual,
              f16* __restrict__ x16, f16* __restrict__ sv16,
              float* __restrict__ xg, float* __restrict__ dcp) {
  const int id = blockIdx.x * 256 + threadIdx.x;
  const bool isx = id < (BATCH * DIM / 8);
  const int lid = isx ? id : id - (BATCH * DIM / 8);
  const int row = lid >> 5;
  const int k0  = (lid & 31) << 3;

  const float* src = (isx ? x : sv) + (size_t)row * DIM + k0;
  float4 u = *(const float4*)(src);
  float4 v = *(const float4*)(src + 4);

  float sq = u.x*u.x + u.y*u.y + u.z*u.z + u.w*u.w
           + v.x*v.x + v.y*v.y + v.z*v.z + v.w*v.w;
  #pragma unroll
  for (int m = 1; m <= 16; m <<= 1) sq += __shfl_xor(sq, m, 32);
  if ((lid & 31) == 0) {
    float g = -(GAMMA * LOG2E) * sq;
    if (isx) xg[row] = g;
    else     dcp[row] = dual[row] * __builtin_amdgcn_exp2f(g);
  }

  f16x8 h;
  h[0] = (f16)(ALPHA * u.x); h[1] = (f16)(ALPHA * u.y);
  h[2] = (f16)(ALPHA * u.z); h[3] = (f16)(ALPHA * u.w);
  h[4] = (f16)(ALPHA * v.x); h[5] = (f16)(ALPHA * v.y);
  h[6] = (f16)(ALPHA * v.z); h[7] = (f16)(ALPHA * v.w);

  const int bt = row >> 8;
  const int r  = row & 255;
  const int kc = k0 >> 5;
  const int c  = (k0 >> 3) & 3;
  f16* dst = (isx ? x16 : sv16) + (size_t)(bt * NKC + kc) * TILE_F16 + (c * 256 + r) * 8;
  *(f16x8*)dst = h;
}

// ---------------- main fused MFMA kernel (counted-vmcnt 3-deep pipeline) ----
// 512 threads = 8 waves (4 wb x 2 wn); wave tile 64 rows x 128 cols as
// 2x4 grid of mfma_f32_32x32x16_f16. Three 32KB LDS buffers; stage(t+2)
// issued at iter t; s_waitcnt vmcnt(4) (never 0 until the last iter) so
// prefetch stays in flight across barriers. Epilogue dcp factors live in
// LDS (not regs) to keep unified VGPR+AGPR demand under the 256/wave cap.
__global__ __launch_bounds__(512, 2)
void svm_main(const f16* __restrict__ x16, const f16* __restrict__ sv16,
              const float* __restrict__ dcp, float* __restrict__ partial) {
  __shared__ f16 lds[3][2 * TILE_F16];   // 96KB
  __shared__ float dcpl[NST * 256];      // 4KB

  const int tid = threadIdx.x;
  const int w   = tid >> 6;
  const int l   = tid & 63;
  const int lr  = l & 31;
  const int lh  = l >> 5;
  const int wb  = w >> 1;        // 0..3 : 64-row strip
  const int wn  = w & 1;         // 0..1 : 128-col strip
  const int sch = blockIdx.x;    // 0..7  (XCD-local s-chunk)
  const int bt  = blockIdx.y;    // 0..31
  const int stile0 = sch * NST;

  // dcp factors for this block's 4 s-tiles -> LDS (once, before the pipeline
  // so their vmcnt retires before counting starts).
  {
    float2 dv2 = *(const float2*)&dcp[stile0 * 256 + tid * 2];
    *(float2*)&dcpl[tid * 2] = dv2;
  }
  __syncthreads();   // drains vmcnt + publishes dcpl

  auto stage = [&](f16* dst, int stile, int kc) {
    const f16* xb = x16  + (size_t)(bt * NKC + kc) * TILE_F16;
    const f16* sb = sv16 + (size_t)(stile * NKC + kc) * TILE_F16;
    #pragma unroll
    for (int j = 0; j < 4; ++j) {
      const int r = w * 4 + j;                       // wave-uniform chunk id
      const f16* src = (r < 16) ? (xb + r * 512 + l * 8)
                                : (sb + (r - 16) * 512 + l * 8);
      gload_lds16(src, dst + r * 512);
    }
  };

  float ctr[2][16];
  #pragma unroll
  for (int m = 0; m < 2; ++m)
    #pragma unroll
    for (int r = 0; r < 16; ++r) ctr[m][r] = 0.f;

  stage(&lds[0][0], stile0, 0);
  stage(&lds[1][0], stile0, 1);
  int ib = 0;

  #pragma unroll 1
  for (int st = 0; st < NST; ++st) {
    f32x16 acc[2][4];
    #pragma unroll
    for (int m = 0; m < 2; ++m)
      #pragma unroll
      for (int n = 0; n < 4; ++n)
        #pragma unroll
        for (int r = 0; r < 16; ++r) acc[m][n][r] = 0.f;

    #pragma unroll 1
    for (int kc = 0; kc < NKC; ++kc) {
      // ---- phase boundary: wait stage(t) landed (keep stage(t+1) in flight)
      __builtin_amdgcn_sched_barrier(0);
      if (st == NST - 1 && kc == NKC - 1)
        asm volatile("s_waitcnt vmcnt(0)" ::: "memory");
      else
        asm volatile("s_waitcnt vmcnt(4)" ::: "memory");
      __builtin_amdgcn_s_barrier();
      __builtin_amdgcn_sched_barrier(0);

      // ---- issue stage(t+2) into the buffer read at t-1
      const int t2 = st * NKC + kc + 2;
      int ib2 = ib + 2; if (ib2 >= 3) ib2 -= 3;
      if (t2 < NITER)
        stage(&lds[ib2][0], stile0 + (t2 >> 3), t2 & 7);

      // ---- compute on buf[ib]: 2 phases of {6 ds_read_b128, 8 MFMA}
      const f16* buf = &lds[ib][0];
      #pragma unroll
      for (int ks = 0; ks < 2; ++ks) {
        const int ko = (ks * 2 + lh) * 256;
        f16x8 a0 = *(const f16x8*)&buf[(ko + wb * 64 +  0 + lr) * 8];
        f16x8 a1 = *(const f16x8*)&buf[(ko + wb * 64 + 32 + lr) * 8];
        f16x8 b0 = *(const f16x8*)&buf[TILE_F16 + (ko + wn * 128 +  0 + lr) * 8];
        f16x8 b1 = *(const f16x8*)&buf[TILE_F16 + (ko + wn * 128 + 32 + lr) * 8];
        f16x8 b2 = *(const f16x8*)&buf[TILE_F16 + (ko + wn * 128 + 64 + lr) * 8];
        f16x8 b3 = *(const f16x8*)&buf[TILE_F16 + (ko + wn * 128 + 96 + lr) * 8];
        __builtin_amdgcn_s_setprio(1);
        acc[0][0] = __builtin_amdgcn_mfma_f32_32x32x16_f16(a0, b0, acc[0][0], 0, 0, 0);
        acc[0][1] = __builtin_amdgcn_mfma_f32_32x32x16_f16(a0, b1, acc[0][1], 0, 0, 0);
        acc[0][2] = __builtin_amdgcn_mfma_f32_32x32x16_f16(a0, b2, acc[0][2], 0, 0, 0);
        acc[0][3] = __builtin_amdgcn_mfma_f32_32x32x16_f16(a0, b3, acc[0][3], 0, 0, 0);
        acc[1][0] = __builtin_amdgcn_mfma_f32_32x32x16_f16(a1, b0, acc[1][0], 0, 0, 0);
        acc[1][1] = __builtin_amdgcn_mfma_f32_32x32x16_f16(a1, b1, acc[1][1], 0, 0, 0);
        acc[1][2] = __builtin_amdgcn_mfma_f32_32x32x16_f16(a1, b2, acc[1][2], 0, 0, 0);
        acc[1][3] = __builtin_amdgcn_mfma_f32_32x32x16_f16(a1, b3, acc[1][3], 0, 0, 0);
        __builtin_amdgcn_s_setprio(0);
      }
      ib = ib + 1; if (ib >= 3) ib -= 3;
    }

    // ---- fused epilogue for s-tile st (LDS dcp reads: lgkmcnt only)
    #pragma unroll
    for (int n = 0; n < 4; ++n) {
      const float dv = dcpl[st * 256 + wn * 128 + n * 32 + lr];
      #pragma unroll
      for (int m = 0; m < 2; ++m)
        #pragma unroll
        for (int r = 0; r < 16; ++r)
          ctr[m][r] = fmaf(__builtin_amdgcn_exp2f(acc[m][n][r]), dv, ctr[m][r]);
    }
  }

  // ---- reduce ctr across the 32 col-lanes sharing each row set
  #pragma unroll
  for (int m = 0; m < 2; ++m)
    #pragma unroll
    for (int r = 0; r < 16; ++r) {
      float v = ctr[m][r];
      v += __shfl_xor(v, 1, 64);
      v += __shfl_xor(v, 2, 64);
      v += __shfl_xor(v, 4, 64);
      v += __shfl_xor(v, 8, 64);
      v += __shfl_xor(v, 16, 64);
      ctr[m][r] = v;
    }

  __syncthreads();                         // LDS buffers free; reuse for red
  float* red = (float*)&lds[0][0];         // [2][256]
  if (lr == 0) {
    #pragma unroll
    for (int m = 0; m < 2; ++m)
      #pragma unroll
      for (int r = 0; r < 16; ++r) {
        const int rl = wb * 64 + m * 32 + (r & 3) + 8 * (r >> 2) + 4 * lh;
        red[wn * 256 + rl] = ctr[m][r];
      }
  }
  __syncthreads();
  if (tid < 256)
    partial[(size_t)sch * BATCH + bt * 256 + tid] = red[tid] + red[256 + tid];
}

// ---------------- final reduction + x-norm factor ----------------
__global__ __launch_bounds__(256)
void svm_reduce(const float* __restrict__ partial, const float* __restrict__ xg,
                float* __restrict__ out) {
  const int b = blockIdx.x * 256 + threadIdx.x;
  float s = 0.f;
  #pragma unroll
  for (int c = 0; c < SCHUNK; ++c) s += partial[(size_t)c * BATCH + b];
  out[b] = __builtin_amdgcn_exp2f(xg[b]) * s;
}

extern "C" void kernel_launch(void* const* d_in, const int* in_sizes, int n_in,
                              void* d_out, int out_size, void* d_ws, size_t ws_size,
                              hipStream_t stream) {
  const float* x    = (const float*)d_in[0];
  const float* sv   = (const float*)d_in[1];
  const float* dual = (const float*)d_in[2];
  float* out = (float*)d_out;

  f16*   x16     = (f16*)d_ws;                       // 4MB
  f16*   sv16    = x16 + (size_t)BATCH * DIM;        // 4MB
  float* xg      = (float*)(sv16 + (size_t)NUM_SV * DIM);
  float* dcp     = xg + BATCH;
  float* partial = dcp + NUM_SV;                     // SCHUNK * BATCH

  svm_prep<<<(BATCH + NUM_SV) * DIM / 8 / 256, 256, 0, stream>>>(x, sv, dual, x16, sv16, xg, dcp);
  svm_main<<<dim3(SCHUNK, BATCH / 256), 512, 0, stream>>>(x16, sv16, dcp, partial);
  svm_reduce<<<BATCH / 256, 256, 0, stream>>>(partial, xg, out);
}

// Round 6
// 55.030 us; speedup vs baseline: 1.9503x; 1.1041x over previous
//
#include <hip/hip_runtime.h>

#define BATCH 8192
#define NUM_SV 8192
#define DIM 256
#define GAMMA 0.1f
#define LOG2E 1.4426950408889634f
// sqrt(2*GAMMA*LOG2E) : pre-scale so MFMA acc == log2-exponent contribution
#define ALPHA 0.53715827f

#define SCHUNK 8
#define NST 4                 // s-tiles per block
#define NKT 4                 // K-tiles (of 64) per s-tile
#define NITER (NST * NKT)     // 16
#define KC_F16 8192           // one 32-wide k-chunk tile: 256 rows * 32 k f16 (16KB)
#define KT_F16 16384          // one K-tile (64): two contiguous kc blocks (32KB)

typedef _Float16 f16;
typedef __attribute__((ext_vector_type(8))) _Float16 f16x8;
typedef __attribute__((ext_vector_type(16))) float f32x16;

__device__ __forceinline__ void gload_lds16(const f16* g, f16* l) {
  __builtin_amdgcn_global_load_lds((const __attribute__((address_space(1))) void*)g,
                                   (__attribute__((address_space(3))) void*)l, 16, 0, 0);
}

// ---------------- pre-pass: scaled fp16 tiled copies + norms + dcp ----------
// Layout per (256-row tile, 32-wide k-chunk): [c=4][row=256][8 f16] (16KB),
// kc-major within a row-tile -> a K=64 tile is 32KB contiguous.
__global__ __launch_bounds__(256)
void svm_prep(const float* __restrict__ x, const float* __restrict__ sv,
              const float* __restrict__ dual,
              f16* __restrict__ x16, f16* __restrict__ sv16,
              float* __restrict__ xg, float* __restrict__ dcp) {
  const int id = blockIdx.x * 256 + threadIdx.x;
  const bool isx = id < (BATCH * DIM / 8);
  const int lid = isx ? id : id - (BATCH * DIM / 8);
  const int row = lid >> 5;
  const int k0  = (lid & 31) << 3;

  const float* src = (isx ? x : sv) + (size_t)row * DIM + k0;
  float4 u = *(const float4*)(src);
  float4 v = *(const float4*)(src + 4);

  float sq = u.x*u.x + u.y*u.y + u.z*u.z + u.w*u.w
           + v.x*v.x + v.y*v.y + v.z*v.z + v.w*v.w;
  #pragma unroll
  for (int m = 1; m <= 16; m <<= 1) sq += __shfl_xor(sq, m, 32);
  if ((lid & 31) == 0) {
    float g = -(GAMMA * LOG2E) * sq;
    if (isx) xg[row] = g;
    else     dcp[row] = dual[row] * __builtin_amdgcn_exp2f(g);
  }

  f16x8 h;
  h[0] = (f16)(ALPHA * u.x); h[1] = (f16)(ALPHA * u.y);
  h[2] = (f16)(ALPHA * u.z); h[3] = (f16)(ALPHA * u.w);
  h[4] = (f16)(ALPHA * v.x); h[5] = (f16)(ALPHA * v.y);
  h[6] = (f16)(ALPHA * v.z); h[7] = (f16)(ALPHA * v.w);

  const int bt = row >> 8;
  const int r  = row & 255;
  const int kc = k0 >> 5;           // 32-wide k-chunk 0..7
  const int c  = (k0 >> 3) & 3;     // 8-wide sub-chunk within
  f16* dst = (isx ? x16 : sv16) + (size_t)(bt * 8 + kc) * KC_F16 + (c * 256 + r) * 8;
  *(f16x8*)dst = h;
}

// ---------------- main fused MFMA kernel (BK=64, dbuf, 1 barrier/step) -----
// 512 threads = 8 waves (4 wb x 2 wn); wave tile 64 rows x 128 cols as
// 2x4 grid of mfma_f32_32x32x16_f16; 32 MFMA per wave per K=64 step.
__global__ __launch_bounds__(512, 2)
void svm_main(const f16* __restrict__ x16, const f16* __restrict__ sv16,
              const float* __restrict__ dcp, float* __restrict__ partial) {
  __shared__ f16 lds[2][2 * KT_F16];   // 2 x (A 32KB + B 32KB) = 128KB
  __shared__ float dcpl[NST * 256];    // 4KB

  const int tid = threadIdx.x;
  const int w   = tid >> 6;
  const int l   = tid & 63;
  const int lr  = l & 31;
  const int lh  = l >> 5;
  const int wb  = w >> 1;        // 0..3 : 64-row strip
  const int wn  = w & 1;         // 0..1 : 128-col strip
  const int sch = blockIdx.x;    // 0..7  (XCD-local s-chunk)
  const int bt  = blockIdx.y;    // 0..31
  const int stile0 = sch * NST;

  // dcp factors for this block's 4 s-tiles -> LDS (once, pre-pipeline)
  {
    float2 dv2 = *(const float2*)&dcp[stile0 * 256 + tid * 2];
    *(float2*)&dcpl[tid * 2] = dv2;
  }

  // stage one K=64 tile (A 32KB + B 32KB) into buffer dst
  auto stage = [&](f16* dst, int stile, int kt) {
    const f16* xA = x16  + (size_t)(bt * 8 + kt * 2) * KC_F16;
    const f16* sB = sv16 + (size_t)(stile * 8 + kt * 2) * KC_F16;
    #pragma unroll
    for (int i = 0; i < 8; ++i) {
      const int q = i * 512 + tid;   // 16B chunk id; wave-uniform base + l*16
      const f16* src = (i < 4) ? (xA + q * 8) : (sB + (q - 2048) * 8);
      gload_lds16(src, dst + q * 8);
    }
  };

  float ctr[2][16];
  #pragma unroll
  for (int m = 0; m < 2; ++m)
    #pragma unroll
    for (int r = 0; r < 16; ++r) ctr[m][r] = 0.f;

  stage(&lds[0][0], stile0, 0);

  #pragma unroll 1
  for (int st = 0; st < NST; ++st) {
    f32x16 acc[2][4];
    #pragma unroll
    for (int m = 0; m < 2; ++m)
      #pragma unroll
      for (int n = 0; n < 4; ++n)
        #pragma unroll
        for (int r = 0; r < 16; ++r) acc[m][n][r] = 0.f;

    #pragma unroll 1
    for (int kt = 0; kt < NKT; ++kt) {
      const int t = st * NKT + kt;
      __syncthreads();   // buf[t&1] staged-loads drained; prev readers done

      // prefetch next K-tile into the other buffer (free since t-1's barrier)
      if (t + 1 < NITER) {
        const int t1 = t + 1;
        stage(&lds[t1 & 1][0], stile0 + (t1 >> 2), t1 & 3);
      }

      // compute on buf[t&1]: 4 sub-steps of {6 ds_read_b128, 8 MFMA}
      const f16* bufA = &lds[t & 1][0];
      const f16* bufB = bufA + KT_F16;
      #pragma unroll
      for (int ks2 = 0; ks2 < 2; ++ks2) {
        #pragma unroll
        for (int ks = 0; ks < 2; ++ks) {
          const int ko = ks2 * KC_F16 / 8 + (ks * 2 + lh) * 256;  // f16x8 units
          f16x8 a0 = *(const f16x8*)&bufA[(ko + wb * 64 +  0 + lr) * 8];
          f16x8 a1 = *(const f16x8*)&bufA[(ko + wb * 64 + 32 + lr) * 8];
          f16x8 b0 = *(const f16x8*)&bufB[(ko + wn * 128 +  0 + lr) * 8];
          f16x8 b1 = *(const f16x8*)&bufB[(ko + wn * 128 + 32 + lr) * 8];
          f16x8 b2 = *(const f16x8*)&bufB[(ko + wn * 128 + 64 + lr) * 8];
          f16x8 b3 = *(const f16x8*)&bufB[(ko + wn * 128 + 96 + lr) * 8];
          acc[0][0] = __builtin_amdgcn_mfma_f32_32x32x16_f16(a0, b0, acc[0][0], 0, 0, 0);
          acc[0][1] = __builtin_amdgcn_mfma_f32_32x32x16_f16(a0, b1, acc[0][1], 0, 0, 0);
          acc[0][2] = __builtin_amdgcn_mfma_f32_32x32x16_f16(a0, b2, acc[0][2], 0, 0, 0);
          acc[0][3] = __builtin_amdgcn_mfma_f32_32x32x16_f16(a0, b3, acc[0][3], 0, 0, 0);
          acc[1][0] = __builtin_amdgcn_mfma_f32_32x32x16_f16(a1, b0, acc[1][0], 0, 0, 0);
          acc[1][1] = __builtin_amdgcn_mfma_f32_32x32x16_f16(a1, b1, acc[1][1], 0, 0, 0);
          acc[1][2] = __builtin_amdgcn_mfma_f32_32x32x16_f16(a1, b2, acc[1][2], 0, 0, 0);
          acc[1][3] = __builtin_amdgcn_mfma_f32_32x32x16_f16(a1, b3, acc[1][3], 0, 0, 0);
        }
      }
    }

    // ---- fused epilogue for s-tile st (LDS dcp reads: lgkmcnt only)
    #pragma unroll
    for (int n = 0; n < 4; ++n) {
      const float dv = dcpl[st * 256 + wn * 128 + n * 32 + lr];
      #pragma unroll
      for (int m = 0; m < 2; ++m)
        #pragma unroll
        for (int r = 0; r < 16; ++r)
          ctr[m][r] = fmaf(__builtin_amdgcn_exp2f(acc[m][n][r]), dv, ctr[m][r]);
    }
  }

  // ---- reduce ctr across the 32 col-lanes sharing each row set
  #pragma unroll
  for (int m = 0; m < 2; ++m)
    #pragma unroll
    for (int r = 0; r < 16; ++r) {
      float v = ctr[m][r];
      v += __shfl_xor(v, 1, 64);
      v += __shfl_xor(v, 2, 64);
      v += __shfl_xor(v, 4, 64);
      v += __shfl_xor(v, 8, 64);
      v += __shfl_xor(v, 16, 64);
      ctr[m][r] = v;
    }

  __syncthreads();                         // LDS buffers free; reuse for red
  float* red = (float*)&lds[0][0];         // [2][256]
  if (lr == 0) {
    #pragma unroll
    for (int m = 0; m < 2; ++m)
      #pragma unroll
      for (int r = 0; r < 16; ++r) {
        const int rl = wb * 64 + m * 32 + (r & 3) + 8 * (r >> 2) + 4 * lh;
        red[wn * 256 + rl] = ctr[m][r];
      }
  }
  __syncthreads();
  if (tid < 256)
    partial[(size_t)sch * BATCH + bt * 256 + tid] = red[tid] + red[256 + tid];
}

// ---------------- final reduction + x-norm factor ----------------
__global__ __launch_bounds__(256)
void svm_reduce(const float* __restrict__ partial, const float* __restrict__ xg,
                float* __restrict__ out) {
  const int b = blockIdx.x * 256 + threadIdx.x;
  float s = 0.f;
  #pragma unroll
  for (int c = 0; c < SCHUNK; ++c) s += partial[(size_t)c * BATCH + b];
  out[b] = __builtin_amdgcn_exp2f(xg[b]) * s;
}

extern "C" void kernel_launch(void* const* d_in, const int* in_sizes, int n_in,
                              void* d_out, int out_size, void* d_ws, size_t ws_size,
                              hipStream_t stream) {
  const float* x    = (const float*)d_in[0];
  const float* sv   = (const float*)d_in[1];
  const float* dual = (const float*)d_in[2];
  float* out = (float*)d_out;

  f16*   x16     = (f16*)d_ws;                       // 4MB
  f16*   sv16    = x16 + (size_t)BATCH * DIM;        // 4MB
  float* xg      = (float*)(sv16 + (size_t)NUM_SV * DIM);
  float* dcp     = xg + BATCH;
  float* partial = dcp + NUM_SV;                     // SCHUNK * BATCH

  svm_prep<<<(BATCH + NUM_SV) * DIM / 8 / 256, 256, 0, stream>>>(x, sv, dual, x16, sv16, xg, dcp);
  svm_main<<<dim3(SCHUNK, BATCH / 256), 512, 0, stream>>>(x16, sv16, dcp, partial);
  svm_reduce<<<BATCH / 256, 256, 0, stream>>>(partial, xg, out);
}

// Round 7
// 54.671 us; speedup vs baseline: 1.9631x; 1.0066x over previous
//
#include <hip/hip_runtime.h>

#define BATCH 8192
#define NUM_SV 8192
#define DIM 256
#define GAMMA 0.1f
#define LOG2E 1.4426950408889634f
// sqrt(2*GAMMA*LOG2E) : pre-scale so MFMA acc == log2-exponent contribution
#define ALPHA 0.53715827f

#define SCHUNK 8
#define NST 4                 // s-tiles per block
#define NITER 16              // K-tiles of 64 (4 per s-tile x 4 s-tiles)
#define HALF_F16 8192         // half-tile: 128 rows x 64 k = 16KB

typedef _Float16 f16;
typedef __attribute__((ext_vector_type(8))) _Float16 f16x8;
typedef __attribute__((ext_vector_type(16))) float f32x16;

__device__ __forceinline__ void gload_lds16(const f16* g, f16* l) {
  __builtin_amdgcn_global_load_lds((const __attribute__((address_space(1))) void*)g,
                                   (__attribute__((address_space(3))) void*)l, 16, 0, 0);
}

// ---------------- pre-pass: scaled fp16 tiled copies + norms + dcp ----------
// Global layout per 256-row tile: [kt=4][half=2][ks=4][rfrag=4][kchunk=2][row=32][8]
// so a 16KB half-tile stages byte-linearly and fragment ds_read_b128 is
// lane-linear (lane l -> kchunk=l>>5, row=l&31 -> offset l*16B).
__global__ __launch_bounds__(256)
void svm_prep(const float* __restrict__ x, const float* __restrict__ sv,
              const float* __restrict__ dual,
              f16* __restrict__ x16, f16* __restrict__ sv16,
              float* __restrict__ xg, float* __restrict__ dcp) {
  const int id = blockIdx.x * 256 + threadIdx.x;
  const bool isx = id < (BATCH * DIM / 8);
  const int lid = isx ? id : id - (BATCH * DIM / 8);
  const int row = lid >> 5;
  const int k0  = (lid & 31) << 3;

  const float* src = (isx ? x : sv) + (size_t)row * DIM + k0;
  float4 u = *(const float4*)(src);
  float4 v = *(const float4*)(src + 4);

  float sq = u.x*u.x + u.y*u.y + u.z*u.z + u.w*u.w
           + v.x*v.x + v.y*v.y + v.z*v.z + v.w*v.w;
  #pragma unroll
  for (int m = 1; m <= 16; m <<= 1) sq += __shfl_xor(sq, m, 32);
  if ((lid & 31) == 0) {
    float g = -(GAMMA * LOG2E) * sq;
    if (isx) xg[row] = g;
    else     dcp[row] = dual[row] * __builtin_amdgcn_exp2f(g);
  }

  f16x8 h;
  h[0] = (f16)(ALPHA * u.x); h[1] = (f16)(ALPHA * u.y);
  h[2] = (f16)(ALPHA * u.z); h[3] = (f16)(ALPHA * u.w);
  h[4] = (f16)(ALPHA * v.x); h[5] = (f16)(ALPHA * v.y);
  h[6] = (f16)(ALPHA * v.z); h[7] = (f16)(ALPHA * v.w);

  const int tile  = row >> 8;
  const int r     = row & 255;
  const int half  = r >> 7;
  const int rfrag = (r >> 5) & 3;
  const int rowin = r & 31;
  const int kt    = k0 >> 6;
  const int ks    = (k0 >> 4) & 3;
  const int kch   = (k0 >> 3) & 1;
  f16* dst = (isx ? x16 : sv16)
           + (size_t)(((tile * 4 + kt) * 2 + half) * HALF_F16)
           + ks * 2048 + rfrag * 512 + kch * 256 + rowin * 8;
  *(f16x8*)dst = h;
}

// ---------------- main fused MFMA kernel: 4-phase counted-vmcnt schedule ----
// 512 threads = 8 waves (wb=0..3: 64-row strip, wn=0..1: 128-col strip);
// wave tile 64x128 as 2x4 of mfma_f32_32x32x16_f16. K-tile = 64. Per phase:
// {ds_read subtile || stage 1 half-tile -> barrier -> lgkmcnt(0) -> 8 MFMA
//  -> barrier}; vmcnt(2) once per K-tile (prefetch stays in flight).
__global__ __launch_bounds__(512, 2)
void svm_main(const f16* __restrict__ x16, const f16* __restrict__ sv16,
              const float* __restrict__ dcp, float* __restrict__ partial) {
  __shared__ f16 lds[2][2][2][HALF_F16];  // [dbuf][op A/B][half] = 128KB
  __shared__ float dcpl[NST * 256];       // 4KB

  const int tid = threadIdx.x;
  const int w   = tid >> 6;
  const int l   = tid & 63;
  const int lr  = l & 31;
  const int lh  = l >> 5;
  const int wb  = w >> 1;        // 0..3 : 64-row strip
  const int wn  = w & 1;         // 0..1 : 128-col strip
  const int sch = blockIdx.x;
  const int bt  = blockIdx.y;
  const int stile0 = sch * NST;

  // dcp factors -> LDS (pre-pipeline; retires before vmcnt counting starts)
  *(float2*)&dcpl[tid * 2] = *(const float2*)&dcp[stile0 * 256 + tid * 2];

  auto stageA = [&](int ut, int half) {
    const f16* src = x16 + (size_t)(((bt * 4 + (ut & 3)) * 2 + half) * HALF_F16) + tid * 8;
    f16* dst = &lds[ut & 1][0][half][tid * 8];
    gload_lds16(src, dst);
    gload_lds16(src + 4096, dst + 4096);
  };
  auto stageB = [&](int ut, int half) {
    const f16* src = sv16 + (size_t)((((stile0 + (ut >> 2)) * 4 + (ut & 3)) * 2 + half) * HALF_F16) + tid * 8;
    f16* dst = &lds[ut & 1][1][half][tid * 8];
    gload_lds16(src, dst);
    gload_lds16(src + 4096, dst + 4096);
  };

#define LOAD_A(ksh)                                                          \
  do {                                                                       \
    const f16* Ab = &lds[u & 1][0][wb >> 1][(wb & 1) * 1024 + l * 8];        \
    af[0][0] = *(const f16x8*)&Ab[((ksh) * 2 + 0) * 2048];                   \
    af[0][1] = *(const f16x8*)&Ab[((ksh) * 2 + 1) * 2048];                   \
    af[1][0] = *(const f16x8*)&Ab[((ksh) * 2 + 0) * 2048 + 512];             \
    af[1][1] = *(const f16x8*)&Ab[((ksh) * 2 + 1) * 2048 + 512];             \
  } while (0)

#define LOAD_B(nfh, ksh)                                                     \
  do {                                                                       \
    const f16* Bb = &lds[u & 1][1][wn][(nfh) * 1024 + l * 8];                \
    bf[0][0] = *(const f16x8*)&Bb[((ksh) * 2 + 0) * 2048];                   \
    bf[0][1] = *(const f16x8*)&Bb[((ksh) * 2 + 1) * 2048];                   \
    bf[1][0] = *(const f16x8*)&Bb[((ksh) * 2 + 0) * 2048 + 512];             \
    bf[1][1] = *(const f16x8*)&Bb[((ksh) * 2 + 1) * 2048 + 512];             \
  } while (0)

#define PH_SYNC                                                              \
  do {                                                                       \
    __builtin_amdgcn_s_barrier();                                            \
    asm volatile("s_waitcnt lgkmcnt(0)" ::: "memory");                       \
    __builtin_amdgcn_sched_barrier(0);                                       \
  } while (0)

#define MFMA1(m, nf, ksl)                                                    \
  acc[m][nf] = __builtin_amdgcn_mfma_f32_32x32x16_f16(af[m][ksl], bf[(nf) & 1][ksl], acc[m][nf], 0, 0, 0)

#define MFMA_PH(nfh)                                                         \
  do {                                                                       \
    __builtin_amdgcn_s_setprio(1);                                           \
    MFMA1(0, (nfh) * 2 + 0, 0); MFMA1(0, (nfh) * 2 + 1, 0);                  \
    MFMA1(1, (nfh) * 2 + 0, 0); MFMA1(1, (nfh) * 2 + 1, 0);                  \
    MFMA1(0, (nfh) * 2 + 0, 1); MFMA1(0, (nfh) * 2 + 1, 1);                  \
    MFMA1(1, (nfh) * 2 + 0, 1); MFMA1(1, (nfh) * 2 + 1, 1);                  \
    __builtin_amdgcn_s_setprio(0);                                           \
  } while (0)

  f32x16 acc[2][4];
  float ctr[2][16];
  #pragma unroll
  for (int m = 0; m < 2; ++m) {
    #pragma unroll
    for (int n = 0; n < 4; ++n)
      #pragma unroll
      for (int r = 0; r < 16; ++r) acc[m][n][r] = 0.f;
    #pragma unroll
    for (int r = 0; r < 16; ++r) ctr[m][r] = 0.f;
  }

  // prologue: stage K-tiles 0 and 1 (16 gload instrs); allow tile1 in flight
  stageA(0, 0); stageA(0, 1); stageB(0, 0); stageB(0, 1);
  stageA(1, 0); stageA(1, 1); stageB(1, 0); stageB(1, 1);
  asm volatile("s_waitcnt vmcnt(8) lgkmcnt(0)" ::: "memory");
  __builtin_amdgcn_s_barrier();

  f16x8 af[2][2], bf[2][2];

  #pragma unroll 1
  for (int u = 0; u < NITER; ++u) {
    // ph0: quadrant (ks-half 0, nf-half 0)
    LOAD_A(0); LOAD_B(0, 0);
    if (u >= 1 && u < NITER - 1) stageA(u + 1, 1);
    PH_SYNC; MFMA_PH(0);
    __builtin_amdgcn_s_barrier();

    // ph1: (0, 1)  -- A reused
    LOAD_B(1, 0);
    if (u >= 1 && u < NITER - 1) stageB(u + 1, 0);
    PH_SYNC; MFMA_PH(1);
    __builtin_amdgcn_s_barrier();

    // ph2: (1, 1)
    LOAD_A(1); LOAD_B(1, 1);
    if (u >= 1 && u < NITER - 1) stageB(u + 1, 1);
    PH_SYNC; MFMA_PH(1);
    __builtin_amdgcn_s_barrier();

    // ph3: (1, 0)  -- A reused; K-tile boundary: counted vmcnt gate
    LOAD_B(0, 1);
    if (u < NITER - 2) stageA(u + 2, 0);
    PH_SYNC; MFMA_PH(0);
    asm volatile("s_waitcnt vmcnt(2)" ::: "memory");
    __builtin_amdgcn_s_barrier();

    // fused epilogue at s-tile boundary (registers + dcpl LDS reads only)
    if ((u & 3) == 3) {
      const int st = u >> 2;
      #pragma unroll
      for (int nf = 0; nf < 4; ++nf) {
        const float dv = dcpl[st * 256 + wn * 128 + nf * 32 + lr];
        #pragma unroll
        for (int m = 0; m < 2; ++m)
          #pragma unroll
          for (int r = 0; r < 16; ++r) {
            ctr[m][r] = fmaf(__builtin_amdgcn_exp2f(acc[m][nf][r]), dv, ctr[m][r]);
            acc[m][nf][r] = 0.f;
          }
      }
    }
  }

  asm volatile("s_waitcnt vmcnt(0)" ::: "memory");

  // ---- reduce ctr across the 32 col-lanes sharing each row set
  #pragma unroll
  for (int m = 0; m < 2; ++m)
    #pragma unroll
    for (int r = 0; r < 16; ++r) {
      float v = ctr[m][r];
      v += __shfl_xor(v, 1, 64);
      v += __shfl_xor(v, 2, 64);
      v += __shfl_xor(v, 4, 64);
      v += __shfl_xor(v, 8, 64);
      v += __shfl_xor(v, 16, 64);
      ctr[m][r] = v;
    }

  __syncthreads();                         // LDS buffers free; reuse for red
  float* red = (float*)&lds[0][0][0][0];   // [2][256]
  if (lr == 0) {
    #pragma unroll
    for (int m = 0; m < 2; ++m)
      #pragma unroll
      for (int r = 0; r < 16; ++r) {
        const int rl = wb * 64 + m * 32 + (r & 3) + 8 * (r >> 2) + 4 * lh;
        red[wn * 256 + rl] = ctr[m][r];
      }
  }
  __syncthreads();
  if (tid < 256)
    partial[(size_t)sch * BATCH + bt * 256 + tid] = red[tid] + red[256 + tid];
}

// ---------------- final reduction + x-norm factor ----------------
__global__ __launch_bounds__(256)
void svm_reduce(const float* __restrict__ partial, const float* __restrict__ xg,
                float* __restrict__ out) {
  const int b = blockIdx.x * 256 + threadIdx.x;
  float s = 0.f;
  #pragma unroll
  for (int c = 0; c < SCHUNK; ++c) s += partial[(size_t)c * BATCH + b];
  out[b] = __builtin_amdgcn_exp2f(xg[b]) * s;
}

extern "C" void kernel_launch(void* const* d_in, const int* in_sizes, int n_in,
                              void* d_out, int out_size, void* d_ws, size_t ws_size,
                              hipStream_t stream) {
  const float* x    = (const float*)d_in[0];
  const float* sv   = (const float*)d_in[1];
  const float* dual = (const float*)d_in[2];
  float* out = (float*)d_out;

  f16*   x16     = (f16*)d_ws;                       // 4MB
  f16*   sv16    = x16 + (size_t)BATCH * DIM;        // 4MB
  float* xg      = (float*)(sv16 + (size_t)NUM_SV * DIM);
  float* dcp     = xg + BATCH;
  float* partial = dcp + NUM_SV;                     // SCHUNK * BATCH

  svm_prep<<<(BATCH + NUM_SV) * DIM / 8 / 256, 256, 0, stream>>>(x, sv, dual, x16, sv16, xg, dcp);
  svm_main<<<dim3(SCHUNK, BATCH / 256), 512, 0, stream>>>(x16, sv16, dcp, partial);
  svm_reduce<<<BATCH / 256, 256, 0, stream>>>(partial, xg, out);
}